// Round 10
// baseline (73.350 us; speedup 1.0000x reference)
//
#include <hip/hip_runtime.h>
#include <hip/hip_bf16.h>

typedef float f32x4 __attribute__((ext_vector_type(4)));

static constexpr int Bn  = 8;
static constexpr int Cn  = 128;
static constexpr int KKn = 9;
static constexpr int CKn = Cn * KKn;        // 1152
static constexpr int PIX = 64 * 64;         // 4096
static constexpr long long OUT_HALF = (long long)Bn * CKn * PIX; // 37748736

// ---------------------------------------------------------------------------
// Kernel 1: per (b,c) plane, yck[b,c,k] = mean_{h,w} xf[b, c*9+k, h, w]
// via inclusion-exclusion on shifted sums. (R4-proven, unchanged)
// ---------------------------------------------------------------------------
__global__ __launch_bounds__(256) void k_stats(const float* __restrict__ x,
                                               const float* __restrict__ wf,
                                               const float* __restrict__ bf,
                                               float* __restrict__ yck) {
    const int bc = blockIdx.x;               // b*C + c
    const float* xp = x + (size_t)bc * PIX;
    const int t = threadIdx.x;

    float tot = 0.f, r0 = 0.f, r63 = 0.f, c0 = 0.f, c63 = 0.f;
#pragma unroll
    for (int i = 0; i < 4; ++i) {
        int p = (i * 256 + t) * 4;
        float4 v = *reinterpret_cast<const float4*>(xp + p);
        int h = p >> 6;
        int w = p & 63;
        float s = v.x + v.y + v.z + v.w;
        tot += s;
        if (h == 0)  r0  += s;
        if (h == 63) r63 += s;
        if (w == 0)  c0  += v.x;
        if (w == 60) c63 += v.w;
    }

    const int lane = t & 63, wid = t >> 6;
#pragma unroll
    for (int off = 32; off; off >>= 1) {
        tot += __shfl_down(tot, off, 64);
        r0  += __shfl_down(r0,  off, 64);
        r63 += __shfl_down(r63, off, 64);
        c0  += __shfl_down(c0,  off, 64);
        c63 += __shfl_down(c63, off, 64);
    }
    __shared__ float part[4][5];
    __shared__ float S[9];
    if (lane == 0) {
        part[wid][0] = tot; part[wid][1] = r0; part[wid][2] = r63;
        part[wid][3] = c0;  part[wid][4] = c63;
    }
    __syncthreads();
    if (t == 0) {
        float T  = part[0][0] + part[1][0] + part[2][0] + part[3][0];
        float R0 = part[0][1] + part[1][1] + part[2][1] + part[3][1];
        float RB = part[0][2] + part[1][2] + part[2][2] + part[3][2];
        float CL = part[0][3] + part[1][3] + part[2][3] + part[3][3];
        float CR = part[0][4] + part[1][4] + part[2][4] + part[3][4];
        float x00 = xp[0], x0R = xp[63], xB0 = xp[63 * 64], xBR = xp[4095];
#pragma unroll
        for (int dh = -1; dh <= 1; ++dh) {
#pragma unroll
            for (int dw = -1; dw <= 1; ++dw) {
                float rex = (dh == -1) ? RB : (dh == 1 ? R0 : 0.f);
                float cex = (dw == -1) ? CR : (dw == 1 ? CL : 0.f);
                float crn = 0.f;
                if (dh != 0 && dw != 0) {
                    crn = (dh == -1) ? ((dw == -1) ? xBR : xB0)
                                     : ((dw == -1) ? x0R : x00);
                }
                S[(dh + 1) * 3 + (dw + 1)] = T - rex - cex + crn;
            }
        }
    }
    __syncthreads();
    if (t < 9) {
        int o = (bc & 127) * 9 + t;
        const float* wp = wf + o * 9;
        float s = 0.f;
#pragma unroll
        for (int j = 0; j < 9; ++j) s = fmaf(wp[j], S[j], s);
        yck[(size_t)bc * 9 + t] = bf[o] + s * (1.f / 4096.f);
    }
}

// ---------------------------------------------------------------------------
// Gate math (shared): for flat channel f = g*128+cc within batch b:
//   gate(f) = sigmoid(ac) * sigmoid(ak)
//   hc[o]  = relu(sum_n yall[cc*9+n] * wc1[(cc*3+o)*9+n])      o<3
//   ac     = sum_o hc[o] * wc2[(cc*9+g)*3+o]
//   hk[o]  = relu(sum_cc yall[cc*9+g] * wk1[(g*8+o)*128+cc])   o<8
//   ak     = sum_o hk[o] * wk2[(g*128+cc)*8+o]
// ---------------------------------------------------------------------------

// ---------------------------------------------------------------------------
// Kernel 2: conv*gate -> out0 (R4-proven body) with gate computed IN-BLOCK
// from yck (removes the k_gate launch + serialization point).
// ---------------------------------------------------------------------------
__global__ __launch_bounds__(256) void k_out0(const float* __restrict__ x,
                                              const float* __restrict__ wf,
                                              const float* __restrict__ bf,
                                              const float* __restrict__ wc1,
                                              const float* __restrict__ wc2,
                                              const float* __restrict__ wk1,
                                              const float* __restrict__ wk2,
                                              const float* __restrict__ yck,
                                              float* __restrict__ out0) {
    const int bc = blockIdx.x;
    const int b = bc >> 7;
    const int c = bc & 127;
    const float* xp = x + (size_t)bc * PIX;
    const int t = threadIdx.x;

    __shared__ float yall[CKn];              // this batch's yck (c-major)
    __shared__ float hks[KKn][8];            // hk per k (per this block's 9 flats)
    __shared__ float wsh[KKn][KKn];          // [k][tap]
    __shared__ float bsh[KKn];
    __shared__ float gsh[KKn];

    const float* yb = yck + (size_t)b * CKn;
    for (int i = t; i < CKn; i += 256) yall[i] = yb[i];
    if (t < 81) wsh[t / 9][t % 9] = wf[(size_t)(c * 9) * 9 + t];
    if (t < 9)  bsh[t] = bf[c * 9 + t];
    __syncthreads();

    if (t < 72) {
        const int k = t >> 3, o = t & 7;
        const int g = (c * 9 + k) >> 7;
        const float* wp = wk1 + (g * 8 + o) * Cn;
        float s = 0.f;
        for (int cc = 0; cc < Cn; ++cc) s = fmaf(yall[cc * 9 + g], wp[cc], s);
        hks[k][o] = fmaxf(s, 0.f);
    }
    __syncthreads();

    if (t < 9) {
        const int flat = c * 9 + t;
        const int g = flat >> 7, cc = flat & 127;
        float hc[3];
#pragma unroll
        for (int o = 0; o < 3; ++o) {
            float s = 0.f;
#pragma unroll
            for (int n = 0; n < 9; ++n)
                s = fmaf(yall[cc * 9 + n], wc1[(cc * 3 + o) * 9 + n], s);
            hc[o] = fmaxf(s, 0.f);
        }
        float acv = 0.f;
#pragma unroll
        for (int o = 0; o < 3; ++o) acv = fmaf(hc[o], wc2[(cc * 9 + g) * 3 + o], acv);
        float akv = 0.f;
#pragma unroll
        for (int o = 0; o < 8; ++o) akv = fmaf(hks[t][o], wk2[(g * Cn + cc) * 8 + o], akv);
        gsh[t] = (1.f / (1.f + expf(-acv))) * (1.f / (1.f + expf(-akv)));
    }
    __syncthreads();

#pragma unroll
    for (int it = 0; it < 4; ++it) {
        int p = it * 1024 + t * 4;           // 4 consecutive pixels in one row
        int h = p >> 6;
        int w = p & 63;

        float rowv[3][6];
#pragma unroll
        for (int dh = 0; dh < 3; ++dh) {
            int hh = h + dh - 1;
            if (hh < 0 || hh > 63) {
#pragma unroll
                for (int j = 0; j < 6; ++j) rowv[dh][j] = 0.f;
            } else {
                const float* rp = xp + hh * 64 + w;
                float4 cen = *reinterpret_cast<const float4*>(rp);
                rowv[dh][1] = cen.x; rowv[dh][2] = cen.y;
                rowv[dh][3] = cen.z; rowv[dh][4] = cen.w;
                rowv[dh][0] = (w > 0)  ? rp[-1] : 0.f;
                rowv[dh][5] = (w < 60) ? rp[4]  : 0.f;
            }
        }

        size_t outBase = (size_t)bc * 9 * PIX + p;
#pragma unroll
        for (int k = 0; k < 9; ++k) {
            float acc0 = bsh[k], acc1 = bsh[k], acc2 = bsh[k], acc3 = bsh[k];
#pragma unroll
            for (int dh = 0; dh < 3; ++dh) {
#pragma unroll
                for (int dw = 0; dw < 3; ++dw) {
                    float wv = wsh[k][dh * 3 + dw];
                    acc0 = fmaf(rowv[dh][0 + dw], wv, acc0);
                    acc1 = fmaf(rowv[dh][1 + dw], wv, acc1);
                    acc2 = fmaf(rowv[dh][2 + dw], wv, acc2);
                    acc3 = fmaf(rowv[dh][3 + dw], wv, acc3);
                }
            }
            float g = gsh[k];
            f32x4 o0 = { acc0 * g, acc1 * g, acc2 * g, acc3 * g };
            *reinterpret_cast<f32x4*>(out0 + outBase + (size_t)k * PIX) = o0;
        }
    }
}

// ---------------------------------------------------------------------------
// Kernel 3: broadcast gate -> out1 (R4-proven fill body) with gate computed
// IN-BLOCK from yck. Block owns 4 contiguous flat planes (same batch, same g,
// 4 consecutive channels: 4-aligned within the 128-block).
// ---------------------------------------------------------------------------
__global__ __launch_bounds__(256) void k_attn(const float* __restrict__ wc1,
                                              const float* __restrict__ wc2,
                                              const float* __restrict__ wk1,
                                              const float* __restrict__ wk2,
                                              const float* __restrict__ yck,
                                              float* __restrict__ out1) {
    const int blk = blockIdx.x;              // 0..2303
    const int t = threadIdx.x;
    const int p0 = blk * 4;                  // first flat plane (b*1152 + f)
    const int b  = p0 / CKn;
    const int f0 = p0 - b * CKn;
    const int g  = f0 >> 7;
    const int c0 = f0 & 127;

    __shared__ float yall[CKn];
    __shared__ float hko[8];
    __shared__ float acs[4];
    __shared__ float gs[4];

    const float* yb = yck + (size_t)b * CKn;
    for (int i = t; i < CKn; i += 256) yall[i] = yb[i];
    __syncthreads();

    if (t < 8) {                             // hk[g][o]
        const float* wp = wk1 + (g * 8 + t) * Cn;
        float s = 0.f;
        for (int cc = 0; cc < Cn; ++cc) s = fmaf(yall[cc * 9 + g], wp[cc], s);
        hko[t] = fmaxf(s, 0.f);
    } else if (t >= 64 && t < 68) {          // ac for the 4 channels
        const int cc = c0 + (t - 64);
        float hc[3];
#pragma unroll
        for (int o = 0; o < 3; ++o) {
            float s = 0.f;
#pragma unroll
            for (int n = 0; n < 9; ++n)
                s = fmaf(yall[cc * 9 + n], wc1[(cc * 3 + o) * 9 + n], s);
            hc[o] = fmaxf(s, 0.f);
        }
        float acv = 0.f;
#pragma unroll
        for (int o = 0; o < 3; ++o) acv = fmaf(hc[o], wc2[(cc * 9 + g) * 3 + o], acv);
        acs[t - 64] = 1.f / (1.f + expf(-acv));
    }
    __syncthreads();

    if (t < 4) {
        const int cc = c0 + t;
        float akv = 0.f;
#pragma unroll
        for (int o = 0; o < 8; ++o) akv = fmaf(hko[o], wk2[(g * Cn + cc) * 8 + o], akv);
        gs[t] = acs[t] * (1.f / (1.f + expf(-akv)));
    }
    __syncthreads();

#pragma unroll
    for (int i = 0; i < 4; ++i) {
        const float gv1 = gs[i];
        f32x4 gv = { gv1, gv1, gv1, gv1 };
        float* o = out1 + (size_t)(p0 + i) * PIX;
#pragma unroll
        for (int j = 0; j < 4; ++j)
            *reinterpret_cast<f32x4*>(o + j * 1024 + t * 4) = gv;
    }
}

// ---------------------------------------------------------------------------
extern "C" void kernel_launch(void* const* d_in, const int* in_sizes, int n_in,
                              void* d_out, int out_size, void* d_ws, size_t ws_size,
                              hipStream_t stream) {
    const float* x   = (const float*)d_in[0];
    const float* wf  = (const float*)d_in[1];
    const float* bf  = (const float*)d_in[2];
    const float* wc1 = (const float*)d_in[3];
    const float* wc2 = (const float*)d_in[4];
    const float* wk1 = (const float*)d_in[5];
    const float* wk2 = (const float*)d_in[6];

    float* out0 = (float*)d_out;
    float* out1 = out0 + OUT_HALF;

    float* yck = (float*)d_ws;                       // B*C*9 = 9216 floats

    k_stats<<<Bn * Cn, 256, 0, stream>>>(x, wf, bf, yck);
    k_out0<<<Bn * Cn, 256, 0, stream>>>(x, wf, bf, wc1, wc2, wk1, wk2, yck, out0);
    k_attn<<<(Bn * CKn) / 4, 256, 0, stream>>>(wc1, wc2, wk1, wk2, yck, out1);
}

// Round 11
// 67.812 us; speedup vs baseline: 1.0817x; 1.0817x over previous
//
#include <hip/hip_runtime.h>
#include <hip/hip_bf16.h>

typedef float f32x4 __attribute__((ext_vector_type(4)));

static constexpr int Bn  = 8;
static constexpr int Cn  = 128;
static constexpr int KKn = 9;
static constexpr int CKn = Cn * KKn;        // 1152
static constexpr int PIX = 64 * 64;         // 4096
static constexpr long long OUT_HALF = (long long)Bn * CKn * PIX; // 37748736

// ---------------------------------------------------------------------------
// Kernel 1: per (b,c) plane, yck[b,c,k] = mean_{h,w} xf[b, c*9+k, h, w]
// via inclusion-exclusion on shifted sums (no conv materialization).
// ---------------------------------------------------------------------------
__global__ __launch_bounds__(256) void k_stats(const float* __restrict__ x,
                                               const float* __restrict__ wf,
                                               const float* __restrict__ bf,
                                               float* __restrict__ yck) {
    const int bc = blockIdx.x;               // b*C + c
    const float* xp = x + (size_t)bc * PIX;
    const int t = threadIdx.x;

    float tot = 0.f, r0 = 0.f, r63 = 0.f, c0 = 0.f, c63 = 0.f;
#pragma unroll
    for (int i = 0; i < 4; ++i) {
        int p = (i * 256 + t) * 4;
        float4 v = *reinterpret_cast<const float4*>(xp + p);
        int h = p >> 6;
        int w = p & 63;
        float s = v.x + v.y + v.z + v.w;
        tot += s;
        if (h == 0)  r0  += s;
        if (h == 63) r63 += s;
        if (w == 0)  c0  += v.x;
        if (w == 60) c63 += v.w;
    }

    const int lane = t & 63, wid = t >> 6;
#pragma unroll
    for (int off = 32; off; off >>= 1) {
        tot += __shfl_down(tot, off, 64);
        r0  += __shfl_down(r0,  off, 64);
        r63 += __shfl_down(r63, off, 64);
        c0  += __shfl_down(c0,  off, 64);
        c63 += __shfl_down(c63, off, 64);
    }
    __shared__ float part[4][5];
    __shared__ float S[9];
    if (lane == 0) {
        part[wid][0] = tot; part[wid][1] = r0; part[wid][2] = r63;
        part[wid][3] = c0;  part[wid][4] = c63;
    }
    __syncthreads();
    if (t == 0) {
        float T  = part[0][0] + part[1][0] + part[2][0] + part[3][0];
        float R0 = part[0][1] + part[1][1] + part[2][1] + part[3][1];
        float RB = part[0][2] + part[1][2] + part[2][2] + part[3][2];
        float CL = part[0][3] + part[1][3] + part[2][3] + part[3][3];
        float CR = part[0][4] + part[1][4] + part[2][4] + part[3][4];
        float x00 = xp[0], x0R = xp[63], xB0 = xp[63 * 64], xBR = xp[4095];
#pragma unroll
        for (int dh = -1; dh <= 1; ++dh) {
#pragma unroll
            for (int dw = -1; dw <= 1; ++dw) {
                float rex = (dh == -1) ? RB : (dh == 1 ? R0 : 0.f);
                float cex = (dw == -1) ? CR : (dw == 1 ? CL : 0.f);
                float crn = 0.f;
                if (dh != 0 && dw != 0) {
                    crn = (dh == -1) ? ((dw == -1) ? xBR : xB0)
                                     : ((dw == -1) ? x0R : x00);
                }
                S[(dh + 1) * 3 + (dw + 1)] = T - rex - cex + crn;
            }
        }
    }
    __syncthreads();
    if (t < 9) {
        int o = (bc & 127) * 9 + t;
        const float* wp = wf + o * 9;
        float s = 0.f;
#pragma unroll
        for (int j = 0; j < 9; ++j) s = fmaf(wp[j], S[j], s);
        yck[(size_t)bc * 9 + t] = bf[o] + s * (1.f / 4096.f);
    }
}

// ---------------------------------------------------------------------------
// Kernel 2: gate[b, g*C + c] = sigmoid(fc_c)[b,c,g] * sigmoid(fc_k)[b,g,c]
// ---------------------------------------------------------------------------
__global__ __launch_bounds__(128) void k_gate(const float* __restrict__ yck,
                                              const float* __restrict__ wc1,
                                              const float* __restrict__ wc2,
                                              const float* __restrict__ wk1,
                                              const float* __restrict__ wk2,
                                              float* __restrict__ gate) {
    const int b = blockIdx.x;
    const int c = threadIdx.x;               // 0..127

    __shared__ float ylds[Cn][KKn];
    __shared__ float aclds[Cn][KKn];
    __shared__ float hks[KKn][8];

    const float* yp = yck + ((size_t)b * Cn + c) * KKn;
    float yv[KKn];
#pragma unroll
    for (int k = 0; k < 9; ++k) { yv[k] = yp[k]; ylds[c][k] = yv[k]; }

    float hc[3];
#pragma unroll
    for (int o = 0; o < 3; ++o) {
        float s = 0.f;
#pragma unroll
        for (int n = 0; n < 9; ++n) s = fmaf(yv[n], wc1[(c * 3 + o) * 9 + n], s);
        hc[o] = fmaxf(s, 0.f);
    }
#pragma unroll
    for (int n = 0; n < 9; ++n) {
        float s = 0.f;
#pragma unroll
        for (int o = 0; o < 3; ++o) s = fmaf(hc[o], wc2[(c * 9 + n) * 3 + o], s);
        aclds[c][n] = 1.f / (1.f + expf(-s));
    }
    __syncthreads();

    if (c < 72) {
        int g = c / 8, o = c % 8;
        float s = 0.f;
        for (int cc = 0; cc < Cn; ++cc) s = fmaf(ylds[cc][g], wk1[(g * 8 + o) * Cn + cc], s);
        hks[g][o] = fmaxf(s, 0.f);
    }
    __syncthreads();

#pragma unroll
    for (int g = 0; g < 9; ++g) {
        float s = 0.f;
#pragma unroll
        for (int o = 0; o < 8; ++o) s = fmaf(hks[g][o], wk2[(g * Cn + c) * 8 + o], s);
        float ak = 1.f / (1.f + expf(-s));
        gate[(size_t)b * CKn + g * Cn + c] = aclds[c][g] * ak;
    }
}

// ---------------------------------------------------------------------------
// Kernel 3a: conv * gate -> out0 only. 4 px/thread, 1KB/wave contiguous
// stores, plain (cached) stores. 9 write streams per wave.
// ---------------------------------------------------------------------------
__global__ __launch_bounds__(256) void k_out0(const float* __restrict__ x,
                                              const float* __restrict__ wf,
                                              const float* __restrict__ bf,
                                              const float* __restrict__ gate,
                                              float* __restrict__ out0) {
    const int bc = blockIdx.x;
    const int b = bc >> 7;
    const int c = bc & 127;
    const float* xp = x + (size_t)bc * PIX;
    const int t = threadIdx.x;

    __shared__ float wsh[KKn][KKn];          // [k][tap]
    __shared__ float bsh[KKn];
    __shared__ float gsh[KKn];
    if (t < 81) wsh[t / 9][t % 9] = wf[(size_t)(c * 9) * 9 + t];
    if (t < 9) {
        bsh[t] = bf[c * 9 + t];
        gsh[t] = gate[(size_t)b * CKn + c * 9 + t]; // positional flat-channel match
    }
    __syncthreads();

#pragma unroll
    for (int it = 0; it < 4; ++it) {
        int p = it * 1024 + t * 4;           // 4 consecutive pixels in one row
        int h = p >> 6;
        int w = p & 63;

        float rowv[3][6];
#pragma unroll
        for (int dh = 0; dh < 3; ++dh) {
            int hh = h + dh - 1;
            if (hh < 0 || hh > 63) {
#pragma unroll
                for (int j = 0; j < 6; ++j) rowv[dh][j] = 0.f;
            } else {
                const float* rp = xp + hh * 64 + w;
                float4 cen = *reinterpret_cast<const float4*>(rp);
                rowv[dh][1] = cen.x; rowv[dh][2] = cen.y;
                rowv[dh][3] = cen.z; rowv[dh][4] = cen.w;
                rowv[dh][0] = (w > 0)  ? rp[-1] : 0.f;
                rowv[dh][5] = (w < 60) ? rp[4]  : 0.f;
            }
        }

        size_t outBase = (size_t)bc * 9 * PIX + p;
#pragma unroll
        for (int k = 0; k < 9; ++k) {
            float acc0 = bsh[k], acc1 = bsh[k], acc2 = bsh[k], acc3 = bsh[k];
#pragma unroll
            for (int dh = 0; dh < 3; ++dh) {
#pragma unroll
                for (int dw = 0; dw < 3; ++dw) {
                    float wv = wsh[k][dh * 3 + dw];
                    acc0 = fmaf(rowv[dh][0 + dw], wv, acc0);
                    acc1 = fmaf(rowv[dh][1 + dw], wv, acc1);
                    acc2 = fmaf(rowv[dh][2 + dw], wv, acc2);
                    acc3 = fmaf(rowv[dh][3 + dw], wv, acc3);
                }
            }
            float g = gsh[k];
            f32x4 o0 = { acc0 * g, acc1 * g, acc2 * g, acc3 * g };
            *reinterpret_cast<f32x4*>(out0 + outBase + (size_t)k * PIX) = o0;
        }
    }
}

// ---------------------------------------------------------------------------
// Kernel 3b: broadcast gate -> out1 (attn). Pure streaming write, fill-like:
// each block owns 4 contiguous planes (64 KB contiguous), each store
// instruction writes 1 KB contiguous per wave.
// ---------------------------------------------------------------------------
__global__ __launch_bounds__(256) void k_attn(const float* __restrict__ gate,
                                              float* __restrict__ out1) {
    const int blk = blockIdx.x;              // 0..2303
    const int t = threadIdx.x;
    const int p0 = blk * 4;                  // first flat plane (b*1152 + ck)

#pragma unroll
    for (int i = 0; i < 4; ++i) {
        const int plane = p0 + i;
        const int b = plane / CKn;
        const int ck = plane - b * CKn;      // flat channel, positional match
        const float g = gate[(size_t)b * CKn + ck];
        f32x4 gv = { g, g, g, g };
        float* o = out1 + (size_t)plane * PIX;
#pragma unroll
        for (int j = 0; j < 4; ++j)
            *reinterpret_cast<f32x4*>(o + j * 1024 + t * 4) = gv;
    }
}

// ---------------------------------------------------------------------------
extern "C" void kernel_launch(void* const* d_in, const int* in_sizes, int n_in,
                              void* d_out, int out_size, void* d_ws, size_t ws_size,
                              hipStream_t stream) {
    const float* x   = (const float*)d_in[0];
    const float* wf  = (const float*)d_in[1];
    const float* bf  = (const float*)d_in[2];
    const float* wc1 = (const float*)d_in[3];
    const float* wc2 = (const float*)d_in[4];
    const float* wk1 = (const float*)d_in[5];
    const float* wk2 = (const float*)d_in[6];

    float* out0 = (float*)d_out;
    float* out1 = out0 + OUT_HALF;

    float* yck  = (float*)d_ws;                      // B*C*9 = 9216 floats
    float* gate = yck + (size_t)Bn * Cn * KKn;       // B*1152 floats

    k_stats<<<Bn * Cn, 256, 0, stream>>>(x, wf, bf, yck);
    k_gate<<<Bn, 128, 0, stream>>>(yck, wc1, wc2, wk1, wk2, gate);
    k_out0<<<Bn * Cn, 256, 0, stream>>>(x, wf, bf, gate, out0);
    k_attn<<<(Bn * CKn) / 4, 256, 0, stream>>>(gate, out1);
}